// Round 8
// baseline (630.026 us; speedup 1.0000x reference)
//
#include <hip/hip_runtime.h>
#include <hip/hip_bf16.h>
#include <stdint.h>

#define DIN   4096
#define DOUT  4096
#define MROWS 8192   // B*S = 4*2048

typedef __bf16 bf16_t;
typedef __attribute__((ext_vector_type(8))) __bf16 bf16x8;
typedef __attribute__((ext_vector_type(4))) float   f32x4;

__device__ __forceinline__ unsigned short f2bf(float f) {
    union { float f; unsigned u; } v; v.f = f;
    unsigned r = v.u + 0x7FFFu + ((v.u >> 16) & 1u);   // RNE
    return (unsigned short)(r >> 16);
}

// ---------------------------------------------------------------------------
// Kernel 1 (fused prep):
//   blocks [0, 4096):      Wt[n][k] = bf16( base_T[k][n] + c*(2*mask[k][n]-1) )
//   blocks [4096, 8192):   Xb = bf16(x), LANE-COALESCED (1 KB/wave/load).
// R4 defect being fixed: old cvt_x read 4 consecutive float4 per THREAD
// (64 B/lane stride -> each load touches 4 KB using 1 KB; ~8 waves/CU x 4 KB
// windows = L1 thrash boundary -> re-fetch). Now lane i reads base + i*16B.
// ---------------------------------------------------------------------------
__global__ __launch_bounds__(256)
void prep(const float* __restrict__ x,
          const float* __restrict__ baseT,
          const int*   __restrict__ mask,
          const float* __restrict__ coeff,
          unsigned short* __restrict__ Wt,
          unsigned short* __restrict__ xb) {
    __shared__ float tile[64][68];
    const int b = blockIdx.x;
    const int t = threadIdx.x;

    if (b < 4096) {
        // ---- build_wt part (64x64 transpose tile) ----
        const float c = coeff[0];
        const int n0 = (b & 63) * 64;
        const int k0 = (b >> 6) * 64;

        const int kr = t >> 4;
        const int nv = (t & 15) * 4;
#pragma unroll
        for (int i = 0; i < 4; ++i) {
            const int kl = i * 16 + kr;
            const size_t idx = (size_t)(k0 + kl) * DOUT + n0 + nv;
            float4 b4 = *(const float4*)(baseT + idx);
            int4   m4 = *(const int4*)(mask + idx);
            float4 v;
            v.x = b4.x + c * (float)(2 * m4.x - 1);
            v.y = b4.y + c * (float)(2 * m4.y - 1);
            v.z = b4.z + c * (float)(2 * m4.z - 1);
            v.w = b4.w + c * (float)(2 * m4.w - 1);
            *(float4*)&tile[kl][nv] = v;
        }
        __syncthreads();

        const int nr = t >> 4;
        const int kv = (t & 15) * 4;
#pragma unroll
        for (int j = 0; j < 4; ++j) {
            const int nl = j * 16 + nr;
            ushort4 o;
            o.x = f2bf(tile[kv + 0][nl]);
            o.y = f2bf(tile[kv + 1][nl]);
            o.z = f2bf(tile[kv + 2][nl]);
            o.w = f2bf(tile[kv + 3][nl]);
            *(ushort4*)(Wt + (size_t)(n0 + nl) * DIN + k0 + kv) = o;
        }
    } else {
        // ---- cvt part: block handles 2048 float4 (32 KB), 8 rounds ----
        const int bb = b - 4096;                 // 0..4095
        const float4* xv = (const float4*)x;
        uint2* ov = (uint2*)xb;                  // one uint2 = 4 bf16
#pragma unroll
        for (int r = 0; r < 8; ++r) {
            const int i4 = bb * 2048 + r * 256 + t;   // lane-contiguous float4 idx
            float4 a = xv[i4];
            union { ushort4 s; uint2 u; } p;
            p.s = make_ushort4(f2bf(a.x), f2bf(a.y), f2bf(a.z), f2bf(a.w));
            ov[i4] = p.u;
        }
    }
}

// ---------------------------------------------------------------------------
// Kernel 2: out[m][n] = sum_k X[m][k] * Wt[n][k]   (bf16 in, fp32 out)
// Round-0 verified structure (266 us, MfmaUtil 48%, bank conflicts 0):
// 128x128 tile, BK=64, 4 waves, 2-barrier loop, 3-4 blocks/CU -> cross-block
// TLP provides the LDS/MFMA overlap (m114). 8-phase experiments (R1-R4)
// measured 304-320 us at 1 block/CU -> reverted; only NEW change vs round-0
// is the bijective XCD swizzle (T1): each XCD gets a contiguous wg chunk
// (bm fast within chunk) so its ~4 Wt panels stay hot in its private L2
// instead of all 8 XCDs duplicating every panel.
// XOR swizzle (8 chunks/row): phys chunk p at row r holds global chunk
// p ^ (r&7) -> fragment reads cover all 32 banks per 8 rows (conflict-free).
// ---------------------------------------------------------------------------
__global__ __launch_bounds__(256, 2)
void gemm_bt(const unsigned short* __restrict__ X,    // [MROWS][DIN] bf16 bits
             const unsigned short* __restrict__ Wt,   // [DOUT][DIN]  bf16 bits
             float* __restrict__ out) {               // [MROWS][DOUT] fp32
    __shared__ __align__(16) bf16_t sA[128 * 64];     // [m][64k] 16 KB
    __shared__ __align__(16) bf16_t sB[128 * 64];     // [n][64k] 16 KB

    const int tid  = threadIdx.x;
    const int lane = tid & 63;
    const int wv   = tid >> 6;        // 0..3

    // bijective XCD swizzle: 2048 wgs = 8 XCDs x 256
    const int bid = blockIdx.x;
    const int wg  = (bid & 7) * 256 + (bid >> 3);
    const int bm  = wg & 63;          // fast -> bm sweep within XCD chunk
    const int bn  = wg >> 6;          // 0..31

    const int wm   = wv >> 1;         // 0..1
    const int wn   = wv & 1;          // 0..1

    // ---- staging: wave w stages rows w*32..w*32+31 (4 loads of 8 rows).
    //      lane l -> row offset l>>3, phys chunk l&7; swizzled source chunk:
    const int row0  = wv * 32 + (lane >> 3);
    const int kcol  = ((lane & 7) ^ (lane >> 3)) * 8;   // chunk_log * 8
    const unsigned short* gA = X  + (size_t)(bm * 128 + row0) * DIN + kcol;
    const unsigned short* gB = Wt + (size_t)(bn * 128 + row0) * DIN + kcol;
    bf16_t* lA = sA + wv * 2048;      // wave region: 4 KB = 2048 elems
    bf16_t* lB = sB + wv * 2048;

    // ---- fragment read offsets (A: m=lane&15, k=(lane>>4)*8+j per kstep)
    //      row&7 == lane&7 for all fragment rows -> unswizzle with lane&7.
    const int arow  = wm * 64 + (lane & 15);
    const int brow  = wn * 64 + (lane & 15);
    const int koff0 = (((lane >> 4) + 0) ^ (lane & 7)) * 8;  // kstep 0
    const int koff1 = (((lane >> 4) + 4) ^ (lane & 7)) * 8;  // kstep 1

    f32x4 acc[4][4];
#pragma unroll
    for (int i = 0; i < 4; ++i)
#pragma unroll
        for (int j = 0; j < 4; ++j) acc[i][j] = (f32x4){0.f, 0.f, 0.f, 0.f};

    for (int kt = 0; kt < DIN / 64; ++kt) {
#pragma unroll
        for (int i = 0; i < 4; ++i)
            __builtin_amdgcn_global_load_lds(
                (const __attribute__((address_space(1))) void*)(gA + (size_t)i * 8 * DIN),
                (__attribute__((address_space(3))) void*)(lA + i * 512), 16, 0, 0);
#pragma unroll
        for (int i = 0; i < 4; ++i)
            __builtin_amdgcn_global_load_lds(
                (const __attribute__((address_space(1))) void*)(gB + (size_t)i * 8 * DIN),
                (__attribute__((address_space(3))) void*)(lB + i * 512), 16, 0, 0);
        gA += 64; gB += 64;
        __syncthreads();   // tiles resident

#pragma unroll
        for (int ks = 0; ks < 2; ++ks) {
            const int ko = ks ? koff1 : koff0;
            bf16x8 af[4], bfr[4];
#pragma unroll
            for (int mi = 0; mi < 4; ++mi)
                af[mi] = *(const bf16x8*)&sA[(arow + mi * 16) * 64 + ko];
#pragma unroll
            for (int ni = 0; ni < 4; ++ni)
                bfr[ni] = *(const bf16x8*)&sB[(brow + ni * 16) * 64 + ko];
#pragma unroll
            for (int mi = 0; mi < 4; ++mi)
#pragma unroll
                for (int ni = 0; ni < 4; ++ni)
                    acc[mi][ni] = __builtin_amdgcn_mfma_f32_16x16x32_bf16(
                        af[mi], bfr[ni], acc[mi][ni], 0, 0, 0);
        }
        __syncthreads();   // all waves done reading before next stage
    }

    // ---- epilogue: D row = (lane>>4)*4 + r, col = lane&15
    const int crow0 = bm * 128 + wm * 64 + (lane >> 4) * 4;
    const int ccol0 = bn * 128 + wn * 64 + (lane & 15);
#pragma unroll
    for (int mi = 0; mi < 4; ++mi)
#pragma unroll
        for (int ni = 0; ni < 4; ++ni)
#pragma unroll
            for (int r = 0; r < 4; ++r)
                out[(size_t)(crow0 + mi * 16 + r) * DOUT + (ccol0 + ni * 16)] =
                    acc[mi][ni][r];
}

extern "C" void kernel_launch(void* const* d_in, const int* in_sizes, int n_in,
                              void* d_out, int out_size, void* d_ws, size_t ws_size,
                              hipStream_t stream) {
    const float* x     = (const float*)d_in[0];
    const float* baseT = (const float*)d_in[1];
    const int*   mask  = (const int*)d_in[2];
    const float* coeff = (const float*)d_in[3];

    unsigned short* Wt = (unsigned short*)d_ws;                                   // 32 MB
    unsigned short* Xb = (unsigned short*)((char*)d_ws + (size_t)DIN * DOUT * 2); // 64 MB
    float* out = (float*)d_out;

    prep<<<4096 + 4096, 256, 0, stream>>>(x, baseT, mask, coeff, Wt, Xb);

    gemm_bt<<<64 * 32, 256, 0, stream>>>(Xb, Wt, out);
}

// Round 11
// 583.875 us; speedup vs baseline: 1.0790x; 1.0790x over previous
//
#include <hip/hip_runtime.h>
#include <hip/hip_bf16.h>
#include <stdint.h>

#define DIN   4096
#define DOUT  4096
#define MROWS 8192   // B*S = 4*2048

typedef __bf16 bf16_t;
typedef __attribute__((ext_vector_type(8))) __bf16 bf16x8;
typedef __attribute__((ext_vector_type(4))) float   f32x4;

__device__ __forceinline__ unsigned short f2bf(float f) {
    union { float f; unsigned u; } v; v.f = f;
    unsigned r = v.u + 0x7FFFu + ((v.u >> 16) & 1u);   // RNE
    return (unsigned short)(r >> 16);
}

// ---------------------------------------------------------------------------
// Kernel 1 (fused prep):
//   blocks [0, 4096):      Wt[n][k] = bf16( base_T[k][n] + c*(2*mask[k][n]-1) )
//   blocks [4096, 8192):   Xb = bf16(x), lane-coalesced.
// NOTE (R8 finding): non-gemm wall time is ~285 us across FOUR different prep
// structures -> it is dominated by fixed harness reset/memset dispatches, not
// prep code (prep roofline ~60 us). Do not optimize prep further.
// ---------------------------------------------------------------------------
__global__ __launch_bounds__(256)
void prep(const float* __restrict__ x,
          const float* __restrict__ baseT,
          const int*   __restrict__ mask,
          const float* __restrict__ coeff,
          unsigned short* __restrict__ Wt,
          unsigned short* __restrict__ xb) {
    __shared__ float tile[64][68];
    const int b = blockIdx.x;
    const int t = threadIdx.x;

    if (b < 4096) {
        // ---- build_wt part (64x64 transpose tile) ----
        const float c = coeff[0];
        const int n0 = (b & 63) * 64;
        const int k0 = (b >> 6) * 64;

        const int kr = t >> 4;
        const int nv = (t & 15) * 4;
#pragma unroll
        for (int i = 0; i < 4; ++i) {
            const int kl = i * 16 + kr;
            const size_t idx = (size_t)(k0 + kl) * DOUT + n0 + nv;
            float4 b4 = *(const float4*)(baseT + idx);
            int4   m4 = *(const int4*)(mask + idx);
            float4 v;
            v.x = b4.x + c * (float)(2 * m4.x - 1);
            v.y = b4.y + c * (float)(2 * m4.y - 1);
            v.z = b4.z + c * (float)(2 * m4.z - 1);
            v.w = b4.w + c * (float)(2 * m4.w - 1);
            *(float4*)&tile[kl][nv] = v;
        }
        __syncthreads();

        const int nr = t >> 4;
        const int kv = (t & 15) * 4;
#pragma unroll
        for (int j = 0; j < 4; ++j) {
            const int nl = j * 16 + nr;
            ushort4 o;
            o.x = f2bf(tile[kv + 0][nl]);
            o.y = f2bf(tile[kv + 1][nl]);
            o.z = f2bf(tile[kv + 2][nl]);
            o.w = f2bf(tile[kv + 3][nl]);
            *(ushort4*)(Wt + (size_t)(n0 + nl) * DIN + k0 + kv) = o;
        }
    } else {
        // ---- cvt part: block handles 2048 float4 (32 KB), 8 rounds ----
        const int bb = b - 4096;                 // 0..4095
        const float4* xv = (const float4*)x;
        uint2* ov = (uint2*)xb;                  // one uint2 = 4 bf16
#pragma unroll
        for (int r = 0; r < 8; ++r) {
            const int i4 = bb * 2048 + r * 256 + t;   // lane-contiguous float4 idx
            float4 a = xv[i4];
            union { ushort4 s; uint2 u; } p;
            p.s = make_ushort4(f2bf(a.x), f2bf(a.y), f2bf(a.z), f2bf(a.w));
            ov[i4] = p.u;
        }
    }
}

// ---------------------------------------------------------------------------
// Kernel 2: out[m][n] = sum_k X[m][k] * Wt[n][k]   (bf16 in, fp32 out)
// Round-0 verified structure AND mapping (267 us, FETCH 560 MB, MfmaUtil 48%).
// R8 post-mortem: XCD-chunk swizzle made each XCD's concurrent window
// 64bm x 1bn (X working set 64 MB >> 4 MB L2) -> FETCH 1.07 GB, 330 us.
// Default round-robin dispatch with bm=bid&63 gives each XCD ~8bm x 8bn
// (~16 MB window) -- near the L2 scheduling optimum. REVERTED to that.
// Only new lever vs R0: __launch_bounds__(256,4) -> request 4 blocks/CU
// (LDS 4x32=128<=160 KB, regs 56V+64A=120<=128/wave at 4 waves/EU), adding
// TLP to cover the 2-barrier vmcnt(0) drain (R0 ran 3 blocks/CU, Occ 38%).
// XOR swizzle (8 chunks/row): phys chunk p at row r holds global chunk
// p ^ (r&7) -> fragment reads cover all 32 banks per 8 rows (conflict-free).
// ---------------------------------------------------------------------------
__global__ __launch_bounds__(256, 4)
void gemm_bt(const unsigned short* __restrict__ X,    // [MROWS][DIN] bf16 bits
             const unsigned short* __restrict__ Wt,   // [DOUT][DIN]  bf16 bits
             float* __restrict__ out) {               // [MROWS][DOUT] fp32
    __shared__ __align__(16) bf16_t sA[128 * 64];     // [m][64k] 16 KB
    __shared__ __align__(16) bf16_t sB[128 * 64];     // [n][64k] 16 KB

    const int tid  = threadIdx.x;
    const int lane = tid & 63;
    const int wv   = tid >> 6;        // 0..3
    const int bm   = blockIdx.x & 63; // 64 m-tiles (fast) -> L2/L3 reuse of Wt
    const int bn   = blockIdx.x >> 6; // 32 n-tiles
    const int wm   = wv >> 1;         // 0..1
    const int wn   = wv & 1;          // 0..1

    // ---- staging: wave w stages rows w*32..w*32+31 (4 loads of 8 rows).
    //      lane l -> row offset l>>3, phys chunk l&7; swizzled source chunk:
    const int row0  = wv * 32 + (lane >> 3);
    const int kcol  = ((lane & 7) ^ (lane >> 3)) * 8;   // chunk_log * 8
    const unsigned short* gA = X  + (size_t)(bm * 128 + row0) * DIN + kcol;
    const unsigned short* gB = Wt + (size_t)(bn * 128 + row0) * DIN + kcol;
    bf16_t* lA = sA + wv * 2048;      // wave region: 4 KB = 2048 elems
    bf16_t* lB = sB + wv * 2048;

    // ---- fragment read offsets (A: m=lane&15, k=(lane>>4)*8+j per kstep)
    //      row&7 == lane&7 for all fragment rows -> unswizzle with lane&7.
    const int arow  = wm * 64 + (lane & 15);
    const int brow  = wn * 64 + (lane & 15);
    const int koff0 = (((lane >> 4) + 0) ^ (lane & 7)) * 8;  // kstep 0
    const int koff1 = (((lane >> 4) + 4) ^ (lane & 7)) * 8;  // kstep 1

    f32x4 acc[4][4];
#pragma unroll
    for (int i = 0; i < 4; ++i)
#pragma unroll
        for (int j = 0; j < 4; ++j) acc[i][j] = (f32x4){0.f, 0.f, 0.f, 0.f};

    for (int kt = 0; kt < DIN / 64; ++kt) {
#pragma unroll
        for (int i = 0; i < 4; ++i)
            __builtin_amdgcn_global_load_lds(
                (const __attribute__((address_space(1))) void*)(gA + (size_t)i * 8 * DIN),
                (__attribute__((address_space(3))) void*)(lA + i * 512), 16, 0, 0);
#pragma unroll
        for (int i = 0; i < 4; ++i)
            __builtin_amdgcn_global_load_lds(
                (const __attribute__((address_space(1))) void*)(gB + (size_t)i * 8 * DIN),
                (__attribute__((address_space(3))) void*)(lB + i * 512), 16, 0, 0);
        gA += 64; gB += 64;
        __syncthreads();   // tiles resident

#pragma unroll
        for (int ks = 0; ks < 2; ++ks) {
            const int ko = ks ? koff1 : koff0;
            bf16x8 af[4], bfr[4];
#pragma unroll
            for (int mi = 0; mi < 4; ++mi)
                af[mi] = *(const bf16x8*)&sA[(arow + mi * 16) * 64 + ko];
#pragma unroll
            for (int ni = 0; ni < 4; ++ni)
                bfr[ni] = *(const bf16x8*)&sB[(brow + ni * 16) * 64 + ko];
#pragma unroll
            for (int mi = 0; mi < 4; ++mi)
#pragma unroll
                for (int ni = 0; ni < 4; ++ni)
                    acc[mi][ni] = __builtin_amdgcn_mfma_f32_16x16x32_bf16(
                        af[mi], bfr[ni], acc[mi][ni], 0, 0, 0);
        }
        __syncthreads();   // all waves done reading before next stage
    }

    // ---- epilogue: D row = (lane>>4)*4 + r, col = lane&15
    const int crow0 = bm * 128 + wm * 64 + (lane >> 4) * 4;
    const int ccol0 = bn * 128 + wn * 64 + (lane & 15);
#pragma unroll
    for (int mi = 0; mi < 4; ++mi)
#pragma unroll
        for (int ni = 0; ni < 4; ++ni)
#pragma unroll
            for (int r = 0; r < 4; ++r)
                out[(size_t)(crow0 + mi * 16 + r) * DOUT + (ccol0 + ni * 16)] =
                    acc[mi][ni][r];
}

extern "C" void kernel_launch(void* const* d_in, const int* in_sizes, int n_in,
                              void* d_out, int out_size, void* d_ws, size_t ws_size,
                              hipStream_t stream) {
    const float* x     = (const float*)d_in[0];
    const float* baseT = (const float*)d_in[1];
    const int*   mask  = (const int*)d_in[2];
    const float* coeff = (const float*)d_in[3];

    unsigned short* Wt = (unsigned short*)d_ws;                                   // 32 MB
    unsigned short* Xb = (unsigned short*)((char*)d_ws + (size_t)DIN * DOUT * 2); // 64 MB
    float* out = (float*)d_out;

    prep<<<4096 + 4096, 256, 0, stream>>>(x, baseT, mask, coeff, Wt, Xb);

    gemm_bt<<<64 * 32, 256, 0, stream>>>(Xb, Wt, out);
}

// Round 14
// 563.517 us; speedup vs baseline: 1.1180x; 1.0361x over previous
//
#include <hip/hip_runtime.h>
#include <hip/hip_bf16.h>
#include <stdint.h>

#define DIN   4096
#define DOUT  4096
#define MROWS 8192   // B*S = 4*2048

typedef __bf16 bf16_t;
typedef __attribute__((ext_vector_type(8))) __bf16 bf16x8;
typedef __attribute__((ext_vector_type(4))) float   f32x4;

__device__ __forceinline__ unsigned short f2bf(float f) {
    union { float f; unsigned u; } v; v.f = f;
    unsigned r = v.u + 0x7FFFu + ((v.u >> 16) & 1u);   // RNE
    return (unsigned short)(r >> 16);
}

// ---------------------------------------------------------------------------
// Kernel 1 (fused prep):
//   blocks [0, 4096):      Wt[n][k] = bf16( base_T[k][n] + c*(2*mask[k][n]-1) )
//   blocks [4096, 8192):   Xb = bf16(x), lane-coalesced.
// R8/R11 finding: non-gemm wall time is ~285 us across FOUR different prep
// structures -> dominated by fixed harness reset dispatches, not prep code
// (prep roofline ~60 us). Do not optimize prep further.
// ---------------------------------------------------------------------------
__global__ __launch_bounds__(256)
void prep(const float* __restrict__ x,
          const float* __restrict__ baseT,
          const int*   __restrict__ mask,
          const float* __restrict__ coeff,
          unsigned short* __restrict__ Wt,
          unsigned short* __restrict__ xb) {
    __shared__ float tile[64][68];
    const int b = blockIdx.x;
    const int t = threadIdx.x;

    if (b < 4096) {
        // ---- build_wt part (64x64 transpose tile) ----
        const float c = coeff[0];
        const int n0 = (b & 63) * 64;
        const int k0 = (b >> 6) * 64;

        const int kr = t >> 4;
        const int nv = (t & 15) * 4;
#pragma unroll
        for (int i = 0; i < 4; ++i) {
            const int kl = i * 16 + kr;
            const size_t idx = (size_t)(k0 + kl) * DOUT + n0 + nv;
            float4 b4 = *(const float4*)(baseT + idx);
            int4   m4 = *(const int4*)(mask + idx);
            float4 v;
            v.x = b4.x + c * (float)(2 * m4.x - 1);
            v.y = b4.y + c * (float)(2 * m4.y - 1);
            v.z = b4.z + c * (float)(2 * m4.z - 1);
            v.w = b4.w + c * (float)(2 * m4.w - 1);
            *(float4*)&tile[kl][nv] = v;
        }
        __syncthreads();

        const int nr = t >> 4;
        const int kv = (t & 15) * 4;
#pragma unroll
        for (int j = 0; j < 4; ++j) {
            const int nl = j * 16 + nr;
            ushort4 o;
            o.x = f2bf(tile[kv + 0][nl]);
            o.y = f2bf(tile[kv + 1][nl]);
            o.z = f2bf(tile[kv + 2][nl]);
            o.w = f2bf(tile[kv + 3][nl]);
            *(ushort4*)(Wt + (size_t)(n0 + nl) * DIN + k0 + kv) = o;
        }
    } else {
        // ---- cvt part: block handles 2048 float4 (32 KB), 8 rounds ----
        const int bb = b - 4096;                 // 0..4095
        const float4* xv = (const float4*)x;
        uint2* ov = (uint2*)xb;                  // one uint2 = 4 bf16
#pragma unroll
        for (int r = 0; r < 8; ++r) {
            const int i4 = bb * 2048 + r * 256 + t;   // lane-contiguous float4 idx
            float4 a = xv[i4];
            union { ushort4 s; uint2 u; } p;
            p.s = make_ushort4(f2bf(a.x), f2bf(a.y), f2bf(a.z), f2bf(a.w));
            ov[i4] = p.u;
        }
    }
}

// ---------------------------------------------------------------------------
// Kernel 2: out[m][n] = sum_k X[m][k] * Wt[n][k]   (bf16 in, fp32 out)
// EXACT round-0 kernel (measured 266-270 us, MfmaUtil 48-50%, FETCH 560 MB,
// VGPR 56, 3 blocks/CU). Session ledger of falsified alternatives:
//   - 8-phase 256^2 counted-vmcnt (3 variants): 304-320 us (lockstep phases
//     serialize ds_read and MFMA at 1 block/CU; template's gain not
//     reproduced on this problem shape)
//   - XCD-chunk swizzle: 330 us (per-XCD X window 64 MB >> 4 MB L2,
//     FETCH 1.07 GB)
//   - __launch_bounds__(256,4): 293 us (VGPR 56->64, occupancy unchanged,
//     MfmaUtil -6pts)
// Default round-robin dispatch + bm=bid&63 gives each XCD a ~8bm x 8bn
// (~16 MB) window -- near the L2 optimum for this grid. 2-barrier loop at
// 3 blocks/CU gets LDS/MFMA overlap from cross-block TLP (m114).
// XOR swizzle (8 chunks/row): phys chunk p at row r holds global chunk
// p ^ (r&7) -> fragment reads cover all 32 banks per 8 rows (conflict-free,
// verified SQ_LDS_BANK_CONFLICT=0).
// ---------------------------------------------------------------------------
__global__ __launch_bounds__(256, 2)
void gemm_bt(const unsigned short* __restrict__ X,    // [MROWS][DIN] bf16 bits
             const unsigned short* __restrict__ Wt,   // [DOUT][DIN]  bf16 bits
             float* __restrict__ out) {               // [MROWS][DOUT] fp32
    __shared__ __align__(16) bf16_t sA[128 * 64];     // [m][64k] 16 KB
    __shared__ __align__(16) bf16_t sB[128 * 64];     // [n][64k] 16 KB

    const int tid  = threadIdx.x;
    const int lane = tid & 63;
    const int wv   = tid >> 6;        // 0..3
    const int bm   = blockIdx.x & 63; // 64 m-tiles (fast) -> L2/L3 reuse of Wt
    const int bn   = blockIdx.x >> 6; // 32 n-tiles
    const int wm   = wv >> 1;         // 0..1
    const int wn   = wv & 1;          // 0..1

    // ---- staging: wave w stages rows w*32..w*32+31 (4 loads of 8 rows).
    //      lane l -> row offset l>>3, phys chunk l&7; swizzled source chunk:
    const int row0  = wv * 32 + (lane >> 3);
    const int kcol  = ((lane & 7) ^ (lane >> 3)) * 8;   // chunk_log * 8
    const unsigned short* gA = X  + (size_t)(bm * 128 + row0) * DIN + kcol;
    const unsigned short* gB = Wt + (size_t)(bn * 128 + row0) * DIN + kcol;
    bf16_t* lA = sA + wv * 2048;      // wave region: 4 KB = 2048 elems
    bf16_t* lB = sB + wv * 2048;

    // ---- fragment read offsets (A: m=lane&15, k=(lane>>4)*8+j per kstep)
    //      row&7 == lane&7 for all fragment rows -> unswizzle with lane&7.
    const int arow  = wm * 64 + (lane & 15);
    const int brow  = wn * 64 + (lane & 15);
    const int koff0 = (((lane >> 4) + 0) ^ (lane & 7)) * 8;  // kstep 0
    const int koff1 = (((lane >> 4) + 4) ^ (lane & 7)) * 8;  // kstep 1

    f32x4 acc[4][4];
#pragma unroll
    for (int i = 0; i < 4; ++i)
#pragma unroll
        for (int j = 0; j < 4; ++j) acc[i][j] = (f32x4){0.f, 0.f, 0.f, 0.f};

    for (int kt = 0; kt < DIN / 64; ++kt) {
#pragma unroll
        for (int i = 0; i < 4; ++i)
            __builtin_amdgcn_global_load_lds(
                (const __attribute__((address_space(1))) void*)(gA + (size_t)i * 8 * DIN),
                (__attribute__((address_space(3))) void*)(lA + i * 512), 16, 0, 0);
#pragma unroll
        for (int i = 0; i < 4; ++i)
            __builtin_amdgcn_global_load_lds(
                (const __attribute__((address_space(1))) void*)(gB + (size_t)i * 8 * DIN),
                (__attribute__((address_space(3))) void*)(lB + i * 512), 16, 0, 0);
        gA += 64; gB += 64;
        __syncthreads();   // tiles resident

#pragma unroll
        for (int ks = 0; ks < 2; ++ks) {
            const int ko = ks ? koff1 : koff0;
            bf16x8 af[4], bfr[4];
#pragma unroll
            for (int mi = 0; mi < 4; ++mi)
                af[mi] = *(const bf16x8*)&sA[(arow + mi * 16) * 64 + ko];
#pragma unroll
            for (int ni = 0; ni < 4; ++ni)
                bfr[ni] = *(const bf16x8*)&sB[(brow + ni * 16) * 64 + ko];
#pragma unroll
            for (int mi = 0; mi < 4; ++mi)
#pragma unroll
                for (int ni = 0; ni < 4; ++ni)
                    acc[mi][ni] = __builtin_amdgcn_mfma_f32_16x16x32_bf16(
                        af[mi], bfr[ni], acc[mi][ni], 0, 0, 0);
        }
        __syncthreads();   // all waves done reading before next stage
    }

    // ---- epilogue: D row = (lane>>4)*4 + r, col = lane&15
    const int crow0 = bm * 128 + wm * 64 + (lane >> 4) * 4;
    const int ccol0 = bn * 128 + wn * 64 + (lane & 15);
#pragma unroll
    for (int mi = 0; mi < 4; ++mi)
#pragma unroll
        for (int ni = 0; ni < 4; ++ni)
#pragma unroll
            for (int r = 0; r < 4; ++r)
                out[(size_t)(crow0 + mi * 16 + r) * DOUT + (ccol0 + ni * 16)] =
                    acc[mi][ni][r];
}

extern "C" void kernel_launch(void* const* d_in, const int* in_sizes, int n_in,
                              void* d_out, int out_size, void* d_ws, size_t ws_size,
                              hipStream_t stream) {
    const float* x     = (const float*)d_in[0];
    const float* baseT = (const float*)d_in[1];
    const int*   mask  = (const int*)d_in[2];
    const float* coeff = (const float*)d_in[3];

    unsigned short* Wt = (unsigned short*)d_ws;                                   // 32 MB
    unsigned short* Xb = (unsigned short*)((char*)d_ws + (size_t)DIN * DOUT * 2); // 64 MB
    float* out = (float*)d_out;

    prep<<<4096 + 4096, 256, 0, stream>>>(x, baseT, mask, coeff, Wt, Xb);

    gemm_bt<<<64 * 32, 256, 0, stream>>>(Xb, Wt, out);
}